// Round 7
// baseline (207.782 us; speedup 1.0000x reference)
//
#include <hip/hip_runtime.h>
#include <hip/hip_cooperative_groups.h>

namespace cg = cooperative_groups;

// Problem constants
#define B_   16
#define C_   512
#define N_   1024   // H*W
#define F_   1024
#define T_   180
#define G_   32

// Workspace layout (float offsets). Total = 36864 + 524288 floats ~= 2.2 MB.
#define WS_MU    0                    // 512  (B*G)
#define WS_RSIG  512                  // 512
#define WS_K     1024                 // 16384 (B*F)
#define WS_V     (1024 + 16384)       // 16384
#define WS_WOS   (1024 + 2*16384)     // 512   WOsum[o] = sum_c wo[o,c]
#define WS_BQS   (WS_WOS + 512)       // 4     BQsum
#define WS_POFF  (WS_BQS + 4)         // 512   per-(b,g) offset partials
#define WS_P     36864                // B*G*N = 524288: P[b,g,n] = sum_{c in g} x*gamma*wqs

// ---------------------------------------------------------------------------
// Single cooperative kernel, 512 blocks x 256 threads (2 blocks/CU resident).
// Block blk -> (b = blk>>5, g = blk&31).
//
// Phase 1 (per block, BALANCED — no serial tails):
//   - x-slab (b,g) -> registers (issued first, covers latency of everything)
//   - redundant WQsum for the block's 16 channels (32 KB of wq, L2-resident)
//   - K/V for 32 f-rows (f = g*32 .. +32) of batch b: 46 KB of wk/wv per block
//     (was: 368 KB on 64 blocks = the single-CU ~15 us tail)
//   - WOsum for o = blk (one wo row, wave 0)
//   - BQsum (block 0, wave 1)
//   - group stats + P + POFF from the register slab
// grid.sync()
// Phase 2 (byte-identical to the measured k_fused):
//   S[n] = sum_g rsig*P + offset; A[n] = rank-1 softmax over f;
//   out[b,o,n] = x + A[n]*WOsum[o] + bo[o]
// ---------------------------------------------------------------------------
__global__ __launch_bounds__(256, 2) void k_all(
    const float* __restrict__ x, const float* __restrict__ gamma,
    const float* __restrict__ beta, const float* __restrict__ cond,
    const float* __restrict__ wq, const float* __restrict__ bq,
    const float* __restrict__ wk, const float* __restrict__ bk,
    const float* __restrict__ wv, const float* __restrict__ bv,
    const float* __restrict__ wo, const float* __restrict__ bo,
    float* __restrict__ ws, float* __restrict__ out)
{
    const int blk = blockIdx.x;
    const int tid = threadIdx.x;
    const int b   = blk >> 5;
    const int g   = blk & 31;

    // ---- LDS (phase 1 + phase 2, disjoint arrays, ~13.6 KB total) ----
    __shared__ __align__(16) float condl[184];
    __shared__ float wqpart[16][16];
    __shared__ float wl[16], bwl[16];
    __shared__ float rs[4], rq[4];
    __shared__ __align__(16) float KV[2 * F_];
    __shared__ float rsigl[32];
    __shared__ float part[8][32];
    __shared__ float pse[8][32], psv[8][32];
    __shared__ float Sl[32], Al[32];
    __shared__ float redmx[4], redmn[4];
    __shared__ float opw;

    // ================= Phase 1 =================
    // x-slab into registers first (latency cover for everything below).
    const float4* xv = (const float4*)(x + (size_t)blk * 16384);
    float4 xr[16];
    #pragma unroll
    for (int j = 0; j < 16; ++j) xr[j] = xv[tid + (j << 8)];

    // cond row for this b -> LDS
    if (tid < T_) condl[tid] = cond[b * T_ + tid];

    // Redundant WQsum partials for this group's 16 channels
    {
        const int j  = tid & 15;   // channel-in-group
        const int oi = tid >> 4;   // 0..15
        const float* wqp = wq + (size_t)oi * C_ + (g << 4) + j;
        float a = 0.f;
        #pragma unroll 8
        for (int k = 0; k < 32; ++k)
            a += wqp[(size_t)(k << 4) * C_];   // o = oi + k*16
        wqpart[oi][j] = a;
    }
    __syncthreads();

    // K/V: 32 f-rows per block, 8 threads per row, float4 over t
    {
        const int r = tid >> 3;            // 0..31
        const int j = tid & 7;             // 0..7
        const int f = (g << 5) + r;        // this block's f-chunk
        const float4* c4  = (const float4*)condl;
        const float4* wk4 = (const float4*)(wk + (size_t)f * T_);  // 720 B rows
        const float4* wv4 = (const float4*)(wv + (size_t)f * T_);
        float aK = 0.f, aV = 0.f;
        for (int t4 = j; t4 < 45; t4 += 8) {
            float4 cf = c4[t4];
            float4 a  = wk4[t4];
            float4 vv = wv4[t4];
            aK = fmaf(cf.x, a.x,  fmaf(cf.y, a.y,  fmaf(cf.z, a.z,  fmaf(cf.w, a.w,  aK))));
            aV = fmaf(cf.x, vv.x, fmaf(cf.y, vv.y, fmaf(cf.z, vv.z, fmaf(cf.w, vv.w, aV))));
        }
        #pragma unroll
        for (int off = 4; off; off >>= 1) {
            aK += __shfl_down(aK, off, 8);
            aV += __shfl_down(aV, off, 8);
        }
        if (j == 0) {
            ws[WS_K + b * F_ + f] = aK + bk[f];
            ws[WS_V + b * F_ + f] = aV + bv[f];
        }
    }

    // WOsum for o = blk (wave 0)
    if (tid < 64) {
        const float4* row = (const float4*)(wo + (size_t)blk * C_);
        float4 p0 = row[tid];
        float4 p1 = row[tid + 64];
        float a = ((p0.x + p0.y) + (p0.z + p0.w)) + ((p1.x + p1.y) + (p1.z + p1.w));
        #pragma unroll
        for (int off = 32; off; off >>= 1) a += __shfl_down(a, off, 64);
        if (tid == 0) ws[WS_WOS + blk] = a;
    }

    // BQsum (block 0, wave 1)
    if (blk == 0 && tid >= 64 && tid < 128) {
        const int l = tid - 64;
        float p = 0.f;
        #pragma unroll
        for (int k = 0; k < 8; ++k) p += bq[l + (k << 6)];
        #pragma unroll
        for (int off = 32; off; off >>= 1) p += __shfl_down(p, off, 64);
        if (l == 0) ws[WS_BQS] = p;
    }

    // WQsum reduce -> wl/bwl
    if (tid < 16) {
        float wqs = 0.f;
        #pragma unroll
        for (int k = 0; k < 16; ++k) wqs += wqpart[k][tid];
        const int c = (g << 4) + tid;
        wl[tid]  = gamma[c] * wqs;
        bwl[tid] = beta[c]  * wqs;
    }
    __syncthreads();

    // Group stats + P + POFF from register slab
    {
        float4 p4 = make_float4(0.f, 0.f, 0.f, 0.f);
        float s = 0.f, sq = 0.f;
        #pragma unroll
        for (int j = 0; j < 16; ++j) {
            float4 p = xr[j];
            s  += (p.x + p.y) + (p.z + p.w);
            sq += p.x * p.x + p.y * p.y + p.z * p.z + p.w * p.w;
            const float wj = wl[j];
            p4.x = fmaf(p.x, wj, p4.x);
            p4.y = fmaf(p.y, wj, p4.y);
            p4.z = fmaf(p.z, wj, p4.z);
            p4.w = fmaf(p.w, wj, p4.w);
        }
        *(float4*)(ws + WS_P + (size_t)blk * 1024 + (tid << 2)) = p4;

        #pragma unroll
        for (int off = 32; off; off >>= 1) {
            s  += __shfl_down(s,  off, 64);
            sq += __shfl_down(sq, off, 64);
        }
        if ((tid & 63) == 0) { rs[tid >> 6] = s; rq[tid >> 6] = sq; }
        __syncthreads();
        if (tid == 0) {
            const float S1 = rs[0] + rs[1] + rs[2] + rs[3];
            const float S2 = rq[0] + rq[1] + rq[2] + rq[3];
            const float mu  = S1 * (1.f / 16384.f);
            const float var = S2 * (1.f / 16384.f) - mu * mu;
            const float rsig = rsqrtf(var + 1e-6f);
            ws[WS_MU   + blk] = mu;
            ws[WS_RSIG + blk] = rsig;
            float sw = 0.f, sbw = 0.f;
            #pragma unroll
            for (int j = 0; j < 16; ++j) { sw += wl[j]; sbw += bwl[j]; }
            ws[WS_POFF + blk] = sbw - mu * rsig * sw;
        }
    }

    // ================= grid-wide barrier =================
    __threadfence();
    cg::this_grid().sync();

    // ================= Phase 2 (measured k_fused body) =================
    const int n0 = g << 5;

    if (tid < 32) rsigl[tid] = ws[WS_RSIG + (b << 5) + tid];
    float op = (tid < 32) ? ws[WS_POFF + (b << 5) + tid] : 0.f;

    const float* Kg = ws + WS_K + b * F_;
    const float* Vg = ws + WS_V + b * F_;
    float mx = -1e30f, mn = 1e30f;
    float2* KV2 = (float2*)KV;
    #pragma unroll
    for (int i = tid; i < F_; i += 256) {
        float kv = Kg[i];
        KV2[i] = make_float2(kv, Vg[i]);    // ds_write_b64
        mx = fmaxf(mx, kv);
        mn = fminf(mn, kv);
    }
    #pragma unroll
    for (int off = 32; off; off >>= 1) {
        op += __shfl_down(op, off, 64);
        mx = fmaxf(mx, __shfl_down(mx, off, 64));
        mn = fminf(mn, __shfl_down(mn, off, 64));
    }
    if ((tid & 63) == 0) {
        redmx[tid >> 6] = mx;
        redmn[tid >> 6] = mn;
        if (tid == 0) opw = op + ws[WS_BQS];
    }
    __syncthreads();
    const float offset = opw;
    const float maxK = fmaxf(fmaxf(redmx[0], redmx[1]), fmaxf(redmx[2], redmx[3]));
    const float minK = fminf(fminf(redmn[0], redmn[1]), fminf(redmn[2], redmn[3]));

    // S over the tile from P (coalesced)
    const int nl = tid & 31;
    const int gq = tid >> 5;              // 0..7, 4 groups each
    {
        const float* Pp = ws + WS_P + ((size_t)((b << 5) + (gq << 2)) << 10) + n0 + nl;
        float acc = 0.f;
        #pragma unroll
        for (int j = 0; j < 4; ++j)
            acc = fmaf(rsigl[(gq << 2) + j], Pp[(size_t)j << 10], acc);
        part[gq][nl] = acc;
    }
    __syncthreads();
    if (tid < 32) {
        float s8 = 0.f;
        #pragma unroll
        for (int j = 0; j < 8; ++j) s8 += part[j][tid];
        Sl[tid] = s8 + offset;
    }
    __syncthreads();

    // rank-1 softmax over f (float2 LDS reads, broadcast)
    const float LOG2E = 1.4426950408889634f;
    const float scale = 0.044194173824159216f;   // 512^-0.5
    const float s  = Sl[nl] * scale;
    const float sl = s * LOG2E;
    const float ml = (s >= 0.f ? maxK : minK) * sl;   // log2-domain row max

    float se = 0.f, sv = 0.f;
    const int fq = tid >> 5;              // 0..7, 128 f each
    const int fbase = fq << 7;
    #pragma unroll 8
    for (int fi = 0; fi < 128; ++fi) {
        float2 kv = KV2[fbase + fi];      // ds_read_b64, same addr across 32 lanes
        float e = exp2f(fmaf(sl, kv.x, -ml));
        se += e;
        sv = fmaf(kv.y, e, sv);
    }
    pse[fq][nl] = se;
    psv[fq][nl] = sv;

    // Hoisted output gathers (overlap with the reduce)
    const int col = tid & 7;    // n4-group: n-offset col*4
    const int row = tid >> 3;   // 0..31
    const float* WOS = ws + WS_WOS;
    float wv_[16], bo_[16];
    #pragma unroll
    for (int p = 0; p < 16; ++p) {
        wv_[p] = WOS[(p << 5) + row];
        bo_[p] = bo[(p << 5) + row];
    }

    __syncthreads();
    if (tid < 32) {
        float den = 0.f, num = 0.f;
        #pragma unroll
        for (int j = 0; j < 8; ++j) { den += pse[j][tid]; num += psv[j][tid]; }
        Al[tid] = num / den;
    }
    __syncthreads();

    // residual + projected-out write (float4 along n)
    float av[4];
    #pragma unroll
    for (int j = 0; j < 4; ++j) av[j] = Al[(col << 2) + j];

    #pragma unroll
    for (int p = 0; p < 16; ++p) {
        const int o = (p << 5) + row;
        const size_t base = (((size_t)(b * C_ + o)) << 10) + n0 + (col << 2);
        float4 x4 = *(const float4*)(x + base);
        float4 ov;
        ov.x = x4.x + fmaf(av[0], wv_[p], bo_[p]);
        ov.y = x4.y + fmaf(av[1], wv_[p], bo_[p]);
        ov.z = x4.z + fmaf(av[2], wv_[p], bo_[p]);
        ov.w = x4.w + fmaf(av[3], wv_[p], bo_[p]);
        *(float4*)(out + base) = ov;
    }
}

extern "C" void kernel_launch(void* const* d_in, const int* in_sizes, int n_in,
                              void* d_out, int out_size, void* d_ws, size_t ws_size,
                              hipStream_t stream) {
    const float* x     = (const float*)d_in[0];
    const float* cond  = (const float*)d_in[1];
    const float* gamma = (const float*)d_in[2];
    const float* beta  = (const float*)d_in[3];
    const float* wq    = (const float*)d_in[4];
    const float* bq    = (const float*)d_in[5];
    const float* wk    = (const float*)d_in[6];
    const float* bk    = (const float*)d_in[7];
    const float* wv    = (const float*)d_in[8];
    const float* bv    = (const float*)d_in[9];
    const float* wo    = (const float*)d_in[10];
    const float* bo    = (const float*)d_in[11];
    float* ws  = (float*)d_ws;
    float* out = (float*)d_out;

    void* args[] = {
        (void*)&x, (void*)&gamma, (void*)&beta, (void*)&cond,
        (void*)&wq, (void*)&bq, (void*)&wk, (void*)&bk,
        (void*)&wv, (void*)&bv, (void*)&wo, (void*)&bo,
        (void*)&ws, (void*)&out
    };
    hipLaunchCooperativeKernel((void*)k_all, dim3(512), dim3(256), args, 0, stream);
}

// Round 10
// 120.271 us; speedup vs baseline: 1.7276x; 1.7276x over previous
//
#include <hip/hip_runtime.h>

// Problem constants
#define B_   16
#define C_   512
#define N_   1024   // H*W
#define F_   1024
#define T_   180
#define G_   32

// Workspace layout (float offsets). Total = 36864 + 524288 floats ~= 2.2 MB.
#define WS_MU    0                    // 512  (B*G)
#define WS_RSIG  512                  // 512
#define WS_K     1024                 // 16384 (B*F)
#define WS_V     (1024 + 16384)       // 16384
#define WS_WOS   (1024 + 2*16384)     // 512   WOsum[o] = sum_c wo[o,c]
#define WS_BQS   (WS_WOS + 512)       // 4     BQsum
#define WS_POFF  (WS_BQS + 4)         // 512   per-(b,g) offset partials
#define WS_P     36864                // B*G*N = 524288: P[b,g,n] = sum_{c in g} x*gamma*wqs

// ---------------------------------------------------------------------------
// Kernel 1 (k_prep): 512 blocks, FULLY BALANCED (R7 phase-1, correctness-
// verified; no single-CU tails). Block blk -> (b = blk>>5, g = blk&31):
//   - redundant WQsum for the block's 16 channels (32 KB of wq, L2-resident)
//   - K/V for 32 f-rows (f = g*32..+32) of batch b: 46 KB wk + 46 KB wv
//     (was 368 KB on 64 blocks = ~15 us single-CU tail in R6)
//   - WOsum for o = blk (one wo row, wave 0); BQsum (block 0, wave 1)
//   - group stats + P + POFF from the x-slab
// ---------------------------------------------------------------------------
__global__ __launch_bounds__(256) void k_prep(
    const float* __restrict__ x, const float* __restrict__ gamma,
    const float* __restrict__ beta, const float* __restrict__ cond,
    const float* __restrict__ wq, const float* __restrict__ bq,
    const float* __restrict__ wk, const float* __restrict__ bk,
    const float* __restrict__ wv, const float* __restrict__ bv,
    const float* __restrict__ wo, float* __restrict__ ws)
{
    const int blk = blockIdx.x;
    const int tid = threadIdx.x;
    const int b   = blk >> 5;
    const int g   = blk & 31;

    __shared__ __align__(16) float condl[184];
    __shared__ float wqpart[16][16];
    __shared__ float wl[16], bwl[16];
    __shared__ float rs[4], rq[4];

    // cond row for this b -> LDS
    if (tid < T_) condl[tid] = cond[b * T_ + tid];

    // Redundant WQsum partials for this group's 16 channels
    {
        const int j  = tid & 15;   // channel-in-group
        const int oi = tid >> 4;   // 0..15
        const float* wqp = wq + (size_t)oi * C_ + (g << 4) + j;
        float a = 0.f;
        #pragma unroll 8
        for (int k = 0; k < 32; ++k)
            a += wqp[(size_t)(k << 4) * C_];   // o = oi + k*16
        wqpart[oi][j] = a;
    }
    __syncthreads();

    // K/V: 32 f-rows per block, 8 threads per row, float4 over t
    {
        const int r = tid >> 3;            // 0..31
        const int j = tid & 7;             // 0..7
        const int f = (g << 5) + r;        // this block's f-chunk
        const float4* c4  = (const float4*)condl;
        const float4* wk4 = (const float4*)(wk + (size_t)f * T_);  // 720 B rows
        const float4* wv4 = (const float4*)(wv + (size_t)f * T_);
        float aK = 0.f, aV = 0.f;
        for (int t4 = j; t4 < 45; t4 += 8) {
            float4 cf = c4[t4];
            float4 a  = wk4[t4];
            float4 vv = wv4[t4];
            aK = fmaf(cf.x, a.x,  fmaf(cf.y, a.y,  fmaf(cf.z, a.z,  fmaf(cf.w, a.w,  aK))));
            aV = fmaf(cf.x, vv.x, fmaf(cf.y, vv.y, fmaf(cf.z, vv.z, fmaf(cf.w, vv.w, aV))));
        }
        #pragma unroll
        for (int off = 4; off; off >>= 1) {
            aK += __shfl_down(aK, off, 8);
            aV += __shfl_down(aV, off, 8);
        }
        if (j == 0) {
            ws[WS_K + b * F_ + f] = aK + bk[f];
            ws[WS_V + b * F_ + f] = aV + bv[f];
        }
    }

    // WOsum for o = blk (wave 0)
    if (tid < 64) {
        const float4* row = (const float4*)(wo + (size_t)blk * C_);
        float4 p0 = row[tid];
        float4 p1 = row[tid + 64];
        float a = ((p0.x + p0.y) + (p0.z + p0.w)) + ((p1.x + p1.y) + (p1.z + p1.w));
        #pragma unroll
        for (int off = 32; off; off >>= 1) a += __shfl_down(a, off, 64);
        if (tid == 0) ws[WS_WOS + blk] = a;
    }

    // BQsum (block 0, wave 1)
    if (blk == 0 && tid >= 64 && tid < 128) {
        const int l = tid - 64;
        float p = 0.f;
        #pragma unroll
        for (int k = 0; k < 8; ++k) p += bq[l + (k << 6)];
        #pragma unroll
        for (int off = 32; off; off >>= 1) p += __shfl_down(p, off, 64);
        if (l == 0) ws[WS_BQS] = p;
    }

    // WQsum reduce -> wl/bwl
    if (tid < 16) {
        float wqs = 0.f;
        #pragma unroll
        for (int k = 0; k < 16; ++k) wqs += wqpart[k][tid];
        const int c = (g << 4) + tid;
        wl[tid]  = gamma[c] * wqs;
        bwl[tid] = beta[c]  * wqs;
    }
    __syncthreads();

    // Group stats + P + POFF from the x-slab
    {
        const float4* xv = (const float4*)(x + (size_t)blk * 16384);
        float4 p4 = make_float4(0.f, 0.f, 0.f, 0.f);
        float s = 0.f, sq = 0.f;
        #pragma unroll
        for (int j = 0; j < 16; ++j) {        // j == local channel
            float4 p = xv[tid + (j << 8)];
            s  += (p.x + p.y) + (p.z + p.w);
            sq += p.x * p.x + p.y * p.y + p.z * p.z + p.w * p.w;
            const float wj = wl[j];
            p4.x = fmaf(p.x, wj, p4.x);
            p4.y = fmaf(p.y, wj, p4.y);
            p4.z = fmaf(p.z, wj, p4.z);
            p4.w = fmaf(p.w, wj, p4.w);
        }
        *(float4*)(ws + WS_P + (size_t)blk * 1024 + (tid << 2)) = p4;

        #pragma unroll
        for (int off = 32; off; off >>= 1) {
            s  += __shfl_down(s,  off, 64);
            sq += __shfl_down(sq, off, 64);
        }
        if ((tid & 63) == 0) { rs[tid >> 6] = s; rq[tid >> 6] = sq; }
        __syncthreads();
        if (tid == 0) {
            const float S1 = rs[0] + rs[1] + rs[2] + rs[3];
            const float S2 = rq[0] + rq[1] + rq[2] + rq[3];
            const float mu  = S1 * (1.f / 16384.f);
            const float var = S2 * (1.f / 16384.f) - mu * mu;
            const float rsig = rsqrtf(var + 1e-6f);
            ws[WS_MU   + blk] = mu;
            ws[WS_RSIG + blk] = rsig;
            float sw = 0.f, sbw = 0.f;
            #pragma unroll
            for (int j = 0; j < 16; ++j) { sw += wl[j]; sbw += bwl[j]; }
            ws[WS_POFF + blk] = sbw - mu * rsig * sw;
        }
    }
}

// ---------------------------------------------------------------------------
// Kernel 2 (k_fused): byte-identical to the measured 124.8/125.9 µs body.
//   S[n] = sum_g rsig*P + offset; A[n] = rank-1 softmax over f;
//   out[b,o,n] = x + A[n]*WOsum[o] + bo[o]
// Grid: 512 blocks = 16 b x 32 n-tiles; 256 threads.
// ---------------------------------------------------------------------------
__global__ __launch_bounds__(256) void k_fused(
    const float* __restrict__ x, const float* __restrict__ bo,
    const float* __restrict__ ws, float* __restrict__ out)
{
    const int b   = blockIdx.x >> 5;
    const int n0  = (blockIdx.x & 31) << 5;
    const int tid = threadIdx.x;

    __shared__ __align__(16) float KV[2 * F_];   // interleaved {K,V} pairs
    __shared__ float rsigl[32];
    __shared__ float part[8][32];
    __shared__ float pse[8][32], psv[8][32];
    __shared__ float Sl[32], Al[32];
    __shared__ float redmx[4], redmn[4];
    __shared__ float opw;

    // ---- Phase A: rsig + offset partials + K/V staging + K extrema ----
    if (tid < 32) rsigl[tid] = ws[WS_RSIG + (b << 5) + tid];
    float op = (tid < 32) ? ws[WS_POFF + (b << 5) + tid] : 0.f;

    const float* Kg = ws + WS_K + b * F_;
    const float* Vg = ws + WS_V + b * F_;
    float mx = -1e30f, mn = 1e30f;
    float2* KV2 = (float2*)KV;
    #pragma unroll
    for (int i = tid; i < F_; i += 256) {
        float kv = Kg[i];
        KV2[i] = make_float2(kv, Vg[i]);    // ds_write_b64
        mx = fmaxf(mx, kv);
        mn = fminf(mn, kv);
    }
    #pragma unroll
    for (int off = 32; off; off >>= 1) {
        op += __shfl_down(op, off, 64);
        mx = fmaxf(mx, __shfl_down(mx, off, 64));
        mn = fminf(mn, __shfl_down(mn, off, 64));
    }
    if ((tid & 63) == 0) {
        redmx[tid >> 6] = mx;
        redmn[tid >> 6] = mn;
        if (tid == 0) opw = op + ws[WS_BQS];
    }
    __syncthreads();
    const float offset = opw;
    const float maxK = fmaxf(fmaxf(redmx[0], redmx[1]), fmaxf(redmx[2], redmx[3]));
    const float minK = fminf(fminf(redmn[0], redmn[1]), fminf(redmn[2], redmn[3]));

    // ---- Phase B: S over the tile from P (coalesced) ----
    const int nl = tid & 31;
    const int gq = tid >> 5;              // 0..7, 4 groups each
    {
        const float* Pp = ws + WS_P + ((size_t)((b << 5) + (gq << 2)) << 10) + n0 + nl;
        float acc = 0.f;
        #pragma unroll
        for (int j = 0; j < 4; ++j)
            acc = fmaf(rsigl[(gq << 2) + j], Pp[(size_t)j << 10], acc);
        part[gq][nl] = acc;
    }
    __syncthreads();
    if (tid < 32) {
        float s8 = 0.f;
        #pragma unroll
        for (int j = 0; j < 8; ++j) s8 += part[j][tid];
        Sl[tid] = s8 + offset;
    }
    __syncthreads();

    // ---- Phase C: rank-1 softmax over f (float2 LDS reads, broadcast) ----
    const float LOG2E = 1.4426950408889634f;
    const float scale = 0.044194173824159216f;   // 512^-0.5
    const float s  = Sl[nl] * scale;
    const float sl = s * LOG2E;
    const float ml = (s >= 0.f ? maxK : minK) * sl;   // log2-domain row max

    float se = 0.f, sv = 0.f;
    const int fq = tid >> 5;              // 0..7, 128 f each
    const int fbase = fq << 7;
    #pragma unroll 8
    for (int fi = 0; fi < 128; ++fi) {
        float2 kv = KV2[fbase + fi];      // ds_read_b64, same addr across 32 lanes
        float e = exp2f(fmaf(sl, kv.x, -ml));
        se += e;
        sv = fmaf(kv.y, e, sv);
    }
    pse[fq][nl] = se;
    psv[fq][nl] = sv;

    // ---- Hoisted Phase-D gathers: overlap with the Phase-C reduce ----
    const int col = tid & 7;    // n4-group: n-offset col*4
    const int row = tid >> 3;   // 0..31
    const float* WOS = ws + WS_WOS;
    float wv_[16], bo_[16];
    #pragma unroll
    for (int p = 0; p < 16; ++p) {
        wv_[p] = WOS[(p << 5) + row];
        bo_[p] = bo[(p << 5) + row];
    }

    __syncthreads();
    if (tid < 32) {
        float den = 0.f, num = 0.f;
        #pragma unroll
        for (int j = 0; j < 8; ++j) { den += pse[j][tid]; num += psv[j][tid]; }
        Al[tid] = num / den;
    }
    __syncthreads();

    // ---- Phase D: residual + projected-out write (float4 along n) ----
    float av[4];
    #pragma unroll
    for (int j = 0; j < 4; ++j) av[j] = Al[(col << 2) + j];

    #pragma unroll
    for (int p = 0; p < 16; ++p) {
        const int o = (p << 5) + row;
        const size_t base = (((size_t)(b * C_ + o)) << 10) + n0 + (col << 2);
        float4 xv = *(const float4*)(x + base);
        float4 ov;
        ov.x = xv.x + fmaf(av[0], wv_[p], bo_[p]);
        ov.y = xv.y + fmaf(av[1], wv_[p], bo_[p]);
        ov.z = xv.z + fmaf(av[2], wv_[p], bo_[p]);
        ov.w = xv.w + fmaf(av[3], wv_[p], bo_[p]);
        *(float4*)(out + base) = ov;
    }
}

extern "C" void kernel_launch(void* const* d_in, const int* in_sizes, int n_in,
                              void* d_out, int out_size, void* d_ws, size_t ws_size,
                              hipStream_t stream) {
    const float* x     = (const float*)d_in[0];
    const float* cond  = (const float*)d_in[1];
    const float* gamma = (const float*)d_in[2];
    const float* beta  = (const float*)d_in[3];
    const float* wq    = (const float*)d_in[4];
    const float* bq    = (const float*)d_in[5];
    const float* wk    = (const float*)d_in[6];
    const float* bk    = (const float*)d_in[7];
    const float* wv    = (const float*)d_in[8];
    const float* bv    = (const float*)d_in[9];
    const float* wo    = (const float*)d_in[10];
    const float* bo    = (const float*)d_in[11];
    float* ws  = (float*)d_ws;
    float* out = (float*)d_out;

    hipLaunchKernelGGL(k_prep, dim3(512), dim3(256), 0, stream,
                       x, gamma, beta, cond, wq, bq, wk, bk, wv, bv, wo, ws);
    hipLaunchKernelGGL(k_fused, dim3(512), dim3(256), 0, stream,
                       x, bo, ws, out);
}

// Round 14
// 119.574 us; speedup vs baseline: 1.7377x; 1.0058x over previous
//
#include <hip/hip_runtime.h>

// Problem constants
#define B_   16
#define C_   512
#define N_   1024   // H*W
#define F_   1024
#define T_   180
#define G_   32

typedef float f32x4 __attribute__((ext_vector_type(4)));   // for nontemporal stores

// Workspace layout (float offsets). Total = 36864 + 524288 floats ~= 2.2 MB.
#define WS_MU    0                    // 512  (B*G)
#define WS_RSIG  512                  // 512
#define WS_K     1024                 // 16384 (B*F)
#define WS_V     (1024 + 16384)       // 16384
#define WS_WOS   (1024 + 2*16384)     // 512   WOsum[o] = sum_c wo[o,c]
#define WS_BQS   (WS_WOS + 512)       // 4     BQsum
#define WS_POFF  (WS_BQS + 4)         // 512   per-(b,g) offset partials
#define WS_P     36864                // B*G*N = 524288: P[b,g,n] = sum_{c in g} x*gamma*wqs

// ---------------------------------------------------------------------------
// Kernel 1 (k_prep): 512 blocks, FULLY BALANCED — byte-identical to the
// measured 120.3 µs version. Block blk -> (b = blk>>5, g = blk&31):
//   - redundant WQsum for the block's 16 channels (32 KB of wq, L2-resident)
//   - K/V for 32 f-rows (f = g*32..+32) of batch b: 46 KB wk + 46 KB wv
//   - WOsum for o = blk (one wo row, wave 0); BQsum (block 0, wave 1)
//   - group stats + P + POFF from the x-slab
// ---------------------------------------------------------------------------
__global__ __launch_bounds__(256) void k_prep(
    const float* __restrict__ x, const float* __restrict__ gamma,
    const float* __restrict__ beta, const float* __restrict__ cond,
    const float* __restrict__ wq, const float* __restrict__ bq,
    const float* __restrict__ wk, const float* __restrict__ bk,
    const float* __restrict__ wv, const float* __restrict__ bv,
    const float* __restrict__ wo, float* __restrict__ ws)
{
    const int blk = blockIdx.x;
    const int tid = threadIdx.x;
    const int b   = blk >> 5;
    const int g   = blk & 31;

    __shared__ __align__(16) float condl[184];
    __shared__ float wqpart[16][16];
    __shared__ float wl[16], bwl[16];
    __shared__ float rs[4], rq[4];

    // cond row for this b -> LDS
    if (tid < T_) condl[tid] = cond[b * T_ + tid];

    // Redundant WQsum partials for this group's 16 channels
    {
        const int j  = tid & 15;   // channel-in-group
        const int oi = tid >> 4;   // 0..15
        const float* wqp = wq + (size_t)oi * C_ + (g << 4) + j;
        float a = 0.f;
        #pragma unroll 8
        for (int k = 0; k < 32; ++k)
            a += wqp[(size_t)(k << 4) * C_];   // o = oi + k*16
        wqpart[oi][j] = a;
    }
    __syncthreads();

    // K/V: 32 f-rows per block, 8 threads per row, float4 over t
    {
        const int r = tid >> 3;            // 0..31
        const int j = tid & 7;             // 0..7
        const int f = (g << 5) + r;        // this block's f-chunk
        const float4* c4  = (const float4*)condl;
        const float4* wk4 = (const float4*)(wk + (size_t)f * T_);  // 720 B rows
        const float4* wv4 = (const float4*)(wv + (size_t)f * T_);
        float aK = 0.f, aV = 0.f;
        for (int t4 = j; t4 < 45; t4 += 8) {
            float4 cf = c4[t4];
            float4 a  = wk4[t4];
            float4 vv = wv4[t4];
            aK = fmaf(cf.x, a.x,  fmaf(cf.y, a.y,  fmaf(cf.z, a.z,  fmaf(cf.w, a.w,  aK))));
            aV = fmaf(cf.x, vv.x, fmaf(cf.y, vv.y, fmaf(cf.z, vv.z, fmaf(cf.w, vv.w, aV))));
        }
        #pragma unroll
        for (int off = 4; off; off >>= 1) {
            aK += __shfl_down(aK, off, 8);
            aV += __shfl_down(aV, off, 8);
        }
        if (j == 0) {
            ws[WS_K + b * F_ + f] = aK + bk[f];
            ws[WS_V + b * F_ + f] = aV + bv[f];
        }
    }

    // WOsum for o = blk (wave 0)
    if (tid < 64) {
        const float4* row = (const float4*)(wo + (size_t)blk * C_);
        float4 p0 = row[tid];
        float4 p1 = row[tid + 64];
        float a = ((p0.x + p0.y) + (p0.z + p0.w)) + ((p1.x + p1.y) + (p1.z + p1.w));
        #pragma unroll
        for (int off = 32; off; off >>= 1) a += __shfl_down(a, off, 64);
        if (tid == 0) ws[WS_WOS + blk] = a;
    }

    // BQsum (block 0, wave 1)
    if (blk == 0 && tid >= 64 && tid < 128) {
        const int l = tid - 64;
        float p = 0.f;
        #pragma unroll
        for (int k = 0; k < 8; ++k) p += bq[l + (k << 6)];
        #pragma unroll
        for (int off = 32; off; off >>= 1) p += __shfl_down(p, off, 64);
        if (l == 0) ws[WS_BQS] = p;
    }

    // WQsum reduce -> wl/bwl
    if (tid < 16) {
        float wqs = 0.f;
        #pragma unroll
        for (int k = 0; k < 16; ++k) wqs += wqpart[k][tid];
        const int c = (g << 4) + tid;
        wl[tid]  = gamma[c] * wqs;
        bwl[tid] = beta[c]  * wqs;
    }
    __syncthreads();

    // Group stats + P + POFF from the x-slab
    {
        const float4* xv = (const float4*)(x + (size_t)blk * 16384);
        float4 p4 = make_float4(0.f, 0.f, 0.f, 0.f);
        float s = 0.f, sq = 0.f;
        #pragma unroll
        for (int j = 0; j < 16; ++j) {        // j == local channel
            float4 p = xv[tid + (j << 8)];
            s  += (p.x + p.y) + (p.z + p.w);
            sq += p.x * p.x + p.y * p.y + p.z * p.z + p.w * p.w;
            const float wj = wl[j];
            p4.x = fmaf(p.x, wj, p4.x);
            p4.y = fmaf(p.y, wj, p4.y);
            p4.z = fmaf(p.z, wj, p4.z);
            p4.w = fmaf(p.w, wj, p4.w);
        }
        *(float4*)(ws + WS_P + (size_t)blk * 1024 + (tid << 2)) = p4;

        #pragma unroll
        for (int off = 32; off; off >>= 1) {
            s  += __shfl_down(s,  off, 64);
            sq += __shfl_down(sq, off, 64);
        }
        if ((tid & 63) == 0) { rs[tid >> 6] = s; rq[tid >> 6] = sq; }
        __syncthreads();
        if (tid == 0) {
            const float S1 = rs[0] + rs[1] + rs[2] + rs[3];
            const float S2 = rq[0] + rq[1] + rq[2] + rq[3];
            const float mu  = S1 * (1.f / 16384.f);
            const float var = S2 * (1.f / 16384.f) - mu * mu;
            const float rsig = rsqrtf(var + 1e-6f);
            ws[WS_MU   + blk] = mu;
            ws[WS_RSIG + blk] = rsig;
            float sw = 0.f, sbw = 0.f;
            #pragma unroll
            for (int j = 0; j < 16; ++j) { sw += wl[j]; sbw += bwl[j]; }
            ws[WS_POFF + blk] = sbw - mu * rsig * sw;
        }
    }
}

// ---------------------------------------------------------------------------
// Kernel 2 (k_fused): measured body + 3 micro-opts:
//   (1) WOS/bo gathers hoisted to kernel top (overlap phases A-C)
//   (2) float4 K/V staging (2 dwordx4 loads/thread instead of 8 scalar)
//   (3) nontemporal out stores (don't evict L3-resident x) — via ext_vector_type
// Grid: 512 blocks = 16 b x 32 n-tiles; 256 threads.
// ---------------------------------------------------------------------------
__global__ __launch_bounds__(256) void k_fused(
    const float* __restrict__ x, const float* __restrict__ bo,
    const float* __restrict__ ws, float* __restrict__ out)
{
    const int b   = blockIdx.x >> 5;
    const int n0  = (blockIdx.x & 31) << 5;
    const int tid = threadIdx.x;

    __shared__ __align__(16) float KV[2 * F_];   // interleaved {K,V} pairs
    __shared__ float rsigl[32];
    __shared__ float part[8][32];
    __shared__ float pse[8][32], psv[8][32];
    __shared__ float Sl[32], Al[32];
    __shared__ float redmx[4], redmn[4];
    __shared__ float opw;

    // ---- Hoisted Phase-D gathers: issued first, overlap all of A-C ----
    const int col = tid & 7;    // n4-group: n-offset col*4
    const int row = tid >> 3;   // 0..31
    const float* WOS = ws + WS_WOS;
    float wv_[16], bo_[16];
    #pragma unroll
    for (int p = 0; p < 16; ++p) {
        wv_[p] = WOS[(p << 5) + row];
        bo_[p] = bo[(p << 5) + row];
    }

    // ---- Phase A: rsig + offset partials + K/V staging + K extrema ----
    if (tid < 32) rsigl[tid] = ws[WS_RSIG + (b << 5) + tid];
    float op = (tid < 32) ? ws[WS_POFF + (b << 5) + tid] : 0.f;

    float2* KV2 = (float2*)KV;
    const float4* Kg4 = (const float4*)(ws + WS_K + b * F_);
    const float4* Vg4 = (const float4*)(ws + WS_V + b * F_);
    float4 k4 = Kg4[tid];
    float4 v4 = Vg4[tid];
    {
        const int i0 = tid << 2;
        KV2[i0 + 0] = make_float2(k4.x, v4.x);
        KV2[i0 + 1] = make_float2(k4.y, v4.y);
        KV2[i0 + 2] = make_float2(k4.z, v4.z);
        KV2[i0 + 3] = make_float2(k4.w, v4.w);
    }
    float mx = fmaxf(fmaxf(k4.x, k4.y), fmaxf(k4.z, k4.w));
    float mn = fminf(fminf(k4.x, k4.y), fminf(k4.z, k4.w));

    #pragma unroll
    for (int off = 32; off; off >>= 1) {
        op += __shfl_down(op, off, 64);
        mx = fmaxf(mx, __shfl_down(mx, off, 64));
        mn = fminf(mn, __shfl_down(mn, off, 64));
    }
    if ((tid & 63) == 0) {
        redmx[tid >> 6] = mx;
        redmn[tid >> 6] = mn;
        if (tid == 0) opw = op + ws[WS_BQS];
    }
    __syncthreads();
    const float offset = opw;
    const float maxK = fmaxf(fmaxf(redmx[0], redmx[1]), fmaxf(redmx[2], redmx[3]));
    const float minK = fminf(fminf(redmn[0], redmn[1]), fminf(redmn[2], redmn[3]));

    // ---- Phase B: S over the tile from P (coalesced) ----
    const int nl = tid & 31;
    const int gq = tid >> 5;              // 0..7, 4 groups each
    {
        const float* Pp = ws + WS_P + ((size_t)((b << 5) + (gq << 2)) << 10) + n0 + nl;
        float acc = 0.f;
        #pragma unroll
        for (int j = 0; j < 4; ++j)
            acc = fmaf(rsigl[(gq << 2) + j], Pp[(size_t)j << 10], acc);
        part[gq][nl] = acc;
    }
    __syncthreads();
    if (tid < 32) {
        float s8 = 0.f;
        #pragma unroll
        for (int j = 0; j < 8; ++j) s8 += part[j][tid];
        Sl[tid] = s8 + offset;
    }
    __syncthreads();

    // ---- Phase C: rank-1 softmax over f (float2 LDS reads, broadcast) ----
    const float LOG2E = 1.4426950408889634f;
    const float scale = 0.044194173824159216f;   // 512^-0.5
    const float s  = Sl[nl] * scale;
    const float sl = s * LOG2E;
    const float ml = (s >= 0.f ? maxK : minK) * sl;   // log2-domain row max

    float se = 0.f, sv = 0.f;
    const int fq = tid >> 5;              // 0..7, 128 f each
    const int fbase = fq << 7;
    #pragma unroll 8
    for (int fi = 0; fi < 128; ++fi) {
        float2 kv = KV2[fbase + fi];      // ds_read_b64, broadcast per 32 lanes
        float e = exp2f(fmaf(sl, kv.x, -ml));
        se += e;
        sv = fmaf(kv.y, e, sv);
    }
    pse[fq][nl] = se;
    psv[fq][nl] = sv;

    __syncthreads();
    if (tid < 32) {
        float den = 0.f, num = 0.f;
        #pragma unroll
        for (int j = 0; j < 8; ++j) { den += pse[j][tid]; num += psv[j][tid]; }
        Al[tid] = num / den;
    }
    __syncthreads();

    // ---- Phase D: residual + projected-out write (float4 along n) ----
    float av[4];
    #pragma unroll
    for (int j = 0; j < 4; ++j) av[j] = Al[(col << 2) + j];

    #pragma unroll
    for (int p = 0; p < 16; ++p) {
        const int o = (p << 5) + row;
        const size_t base = (((size_t)(b * C_ + o)) << 10) + n0 + (col << 2);
        float4 xv = *(const float4*)(x + base);
        f32x4 ov;
        ov.x = xv.x + fmaf(av[0], wv_[p], bo_[p]);
        ov.y = xv.y + fmaf(av[1], wv_[p], bo_[p]);
        ov.z = xv.z + fmaf(av[2], wv_[p], bo_[p]);
        ov.w = xv.w + fmaf(av[3], wv_[p], bo_[p]);
        __builtin_nontemporal_store(ov, (f32x4*)(out + base));
    }
}

extern "C" void kernel_launch(void* const* d_in, const int* in_sizes, int n_in,
                              void* d_out, int out_size, void* d_ws, size_t ws_size,
                              hipStream_t stream) {
    const float* x     = (const float*)d_in[0];
    const float* cond  = (const float*)d_in[1];
    const float* gamma = (const float*)d_in[2];
    const float* beta  = (const float*)d_in[3];
    const float* wq    = (const float*)d_in[4];
    const float* bq    = (const float*)d_in[5];
    const float* wk    = (const float*)d_in[6];
    const float* bk    = (const float*)d_in[7];
    const float* wv    = (const float*)d_in[8];
    const float* bv    = (const float*)d_in[9];
    const float* wo    = (const float*)d_in[10];
    const float* bo    = (const float*)d_in[11];
    float* ws  = (float*)d_ws;
    float* out = (float*)d_out;

    hipLaunchKernelGGL(k_prep, dim3(512), dim3(256), 0, stream,
                       x, gamma, beta, cond, wq, bq, wk, bk, wv, bv, wo, ws);
    hipLaunchKernelGGL(k_fused, dim3(512), dim3(256), 0, stream,
                       x, bo, ws, out);
}